// Round 14
// baseline (45.295 us; speedup 1.0000x reference)
//
#include <hip/hip_runtime.h>
#include <math.h>

#define SCALE 8
#define PSZ 32

// LDS layout constants (u32 / float units)
#define WSTRIDE 41                 // window row stride (odd -> 2-way bank alias max)
#define RSTRIDE 92                 // spec row stride per slot (16B aligned)
#define SSTRIDE (17 * RSTRIDE)     // spec strip stride = 1564

// ---- constant twiddles: W_32^k = cos(2pi k/32) - i sin(2pi k/32), k=0..15 ----
__device__ constexpr float C32[16] = {
     1.000000000000000f,  0.980785280403230f,  0.923879532511287f,  0.831469612302545f,
     0.707106781186548f,  0.555570233019602f,  0.382683432365090f,  0.195090322016128f,
     0.000000000000000f, -0.195090322016128f, -0.382683432365090f, -0.555570233019602f,
    -0.707106781186548f, -0.831469612302545f, -0.923879532511287f, -0.980785280403230f };
__device__ constexpr float S32[16] = {
     0.000000000000000f,  0.195090322016128f,  0.382683432365090f,  0.555570233019602f,
     0.707106781186548f,  0.831469612302545f,  0.923879532511287f,  0.980785280403230f,
     1.000000000000000f,  0.980785280403230f,  0.923879532511287f,  0.831469612302545f,
     0.707106781186548f,  0.555570233019602f,  0.382683432365090f,  0.195090322016128f };

__device__ __forceinline__ constexpr int brev4(int i) {
    return ((i & 1) << 3) | ((i & 2) << 1) | ((i & 4) >> 1) | ((i & 8) >> 3);
}

// in-place 16-point radix-2 DIT FFT, fully unrolled (R9-verified)
__device__ __forceinline__ void fft16(float re[16], float im[16]) {
#pragma unroll
    for (int i = 0; i < 16; ++i) {
        const int j = brev4(i);
        if (j > i) {
            float t = re[i]; re[i] = re[j]; re[j] = t;
            t = im[i]; im[i] = im[j]; im[j] = t;
        }
    }
#pragma unroll
    for (int s = 1; s <= 4; ++s) {
        const int m = 1 << s;
        const int h = m >> 1;
        const int tstep = 32 >> s;
#pragma unroll
        for (int k = 0; k < 16; k += m) {
#pragma unroll
            for (int j = 0; j < h; ++j) {
                const float wr = C32[j * tstep];
                const float wi = -S32[j * tstep];
                const int a = k + j;
                const int b = k + j + h;
                const float tr = wr * re[b] - wi * im[b];
                const float ti = wr * im[b] + wi * re[b];
                re[b] = re[a] - tr; im[b] = im[a] - ti;
                re[a] = re[a] + tr; im[a] = im[a] + ti;
            }
        }
    }
}

// bf16x2 pack/unpack (round-half-up via +0x8000)
__device__ __forceinline__ unsigned pack_bf2(float hi, float lo) {
    const unsigned uh = __float_as_uint(hi) + 0x8000u;
    const unsigned ul = __float_as_uint(lo) + 0x8000u;
    return (uh & 0xFFFF0000u) | (ul >> 16);
}
__device__ __forceinline__ float bf_hi(unsigned u) { return __uint_as_float(u & 0xFFFF0000u); }
__device__ __forceinline__ float bf_lo(unsigned u) { return __uint_as_float(u << 16); }

// ===================== FUSED TILE KERNEL (R14) =====================
// 256-thread block = 2-wide x 8-tall patch tile (16 patches). TWO dispatches
// total (tile + norm): gray fused via a COALESCED cooperative window stage
// (R12's failure was one-row-per-lane 3ch reads; here threads stride the
// contiguous row-segment dimension: consecutive lanes read consecutive
// float4s of a row segment).
//
// Phase 0: stage gray window rows row0..row0+87 x cols col0..col0+39 into LDS
//          win[88][41] (odd stride: phase-1 reads are 2-way aliased = free).
// Phase 1: 176 parity row-FFT tasks (R9-verified DIF): lanes 0..87 EVEN half
//          of row y=tid, lanes 128..215 ODD half of row y=tid-128. Premix
//          directly from LDS window (no 40-reg array; ~36 live). Hermitian
//          bf16x2 -> spec[strip][slot][row], RSTRIDE 92.
// Phase 2: 256 col tasks (16 patches x 16 slots). LOW-LIVENESS: each DIF pass
//          re-reads LDS with paired-quad ds_read_b128 + immediate premix
//          (<=48 live vs R13's u[32]+fft = 75+ live at VGPR_Count=64 ->
//          shuttle tax). Masked log-power (verified weights), 16-lane reduce.
//          Block writes 16 sums + 1 partial max.
__global__ __launch_bounds__(256) void hfdft_tile_kernel(
        const float* __restrict__ x, const float* __restrict__ w,
        float* __restrict__ out, float* __restrict__ partial,
        int W, int mat_w, long long HW) {
    __shared__ float win[88 * WSTRIDE];      // 14,432 B
    __shared__ unsigned spec[2 * SSTRIDE];   // 12,512 B
    __shared__ float red[16];

    const int tid = threadIdx.x;
    const int row0 = blockIdx.y * 64;
    const int col0 = blockIdx.x * 16;

    // ================= phase 0: coalesced gray window stage =================
    {
        const float w0 = w[0], w1 = w[1], w2 = w[2];
        for (int idx = tid; idx < 880; idx += 256) {
            const int row = idx / 10;
            const int f4 = idx - row * 10;
            const float* base = x + (size_t)(row0 + row) * W + col0 + f4 * 4;
            const float4 a = *reinterpret_cast<const float4*>(base);
            const float4 b = *reinterpret_cast<const float4*>(base + HW);
            const float4 c = *reinterpret_cast<const float4*>(base + 2 * HW);
            float* wp = win + row * WSTRIDE + f4 * 4;
            wp[0] = w0 * a.x + w1 * b.x + w2 * c.x;
            wp[1] = w0 * a.y + w1 * b.y + w2 * c.y;
            wp[2] = w0 * a.z + w1 * b.z + w2 * c.z;
            wp[3] = w0 * a.w + w1 * b.w + w2 * c.w;
        }
    }

    __syncthreads();

    // ================= phase 1: row FFTs (176 parity tasks) =================
    const bool is_even = (tid < 88);
    const bool is_odd = (tid >= 128 && tid < 216);
    if (is_even || is_odd) {
        const int y = is_even ? tid : (tid - 128);
        const float* wrow = win + y * WSTRIDE;

        unsigned* sA = spec + y;                 // strip 0: slot k at k*RSTRIDE
        unsigned* sB = spec + SSTRIDE + y;       // strip 1

        float fr[16], fi[16];
        if (is_even) {
#pragma unroll
            for (int i = 0; i < 16; ++i) {
                fr[i] = wrow[i] + wrow[i + 16];          // strip A sums
                fi[i] = wrow[i + 8] + wrow[i + 24];      // strip B sums
            }
            fft16(fr, fi);
            sA[0] = pack_bf2(fr[0], fr[8]);              // slot 0: (F(0), F(16))
            sB[0] = pack_bf2(fi[0], fi[8]);
#pragma unroll
            for (int k2 = 1; k2 <= 7; ++k2) {
                const int e2 = 16 - k2;
                const float far_ = 0.5f * (fr[k2] + fr[e2]);
                const float fai_ = 0.5f * (fi[k2] - fi[e2]);
                const float fbr_ = 0.5f * (fi[k2] + fi[e2]);
                const float fbi_ = 0.5f * (fr[e2] - fr[k2]);
                sA[(2 * k2) * RSTRIDE] = pack_bf2(far_, fai_);
                sB[(2 * k2) * RSTRIDE] = pack_bf2(fbr_, fbi_);
            }
        } else {
#pragma unroll
            for (int i = 0; i < 16; ++i) {
                const float dre = wrow[i] - wrow[i + 16];
                const float dim = wrow[i + 8] - wrow[i + 24];
                fr[i] = dre * C32[i] + dim * S32[i];
                fi[i] = dim * C32[i] - dre * S32[i];
            }
            fft16(fr, fi);
#pragma unroll
            for (int k2 = 0; k2 <= 7; ++k2) {
                const int o2 = 15 - k2;
                const float far_ = 0.5f * (fr[k2] + fr[o2]);
                const float fai_ = 0.5f * (fi[k2] - fi[o2]);
                const float fbr_ = 0.5f * (fi[k2] + fi[o2]);
                const float fbi_ = 0.5f * (fr[o2] - fr[k2]);
                sA[(2 * k2 + 1) * RSTRIDE] = pack_bf2(far_, fai_);
                sB[(2 * k2 + 1) * RSTRIDE] = pack_bf2(fbr_, fbi_);
            }
        }
    }

    __syncthreads();

    // ================= phase 2: col FFTs (256 tasks, low liveness) =================
    {
        const int pl = tid >> 4;
        const int slot = tid & 15;
        const int ph = pl >> 1, strip = pl & 1;
        const uint4* p4 = reinterpret_cast<const uint4*>(
            spec + strip * SSTRIDE + slot * RSTRIDE + ph * 8);
        const float b1f = (slot >= 7) ? 1.0f : 0.0f;
        const float m1f = (slot >= 8) ? 1.0f : 0.0f;

        float s0 = 0.0f, s1 = 0.0f;

        // ---- pass 1: even kr (paired-quad read + premix, <=48 live) ----
        {
            float er[16], ei[16];
#pragma unroll
            for (int q = 0; q < 4; ++q) {
                const uint4 lo = p4[q];
                const uint4 hi = p4[q + 4];
                er[4 * q + 0] = bf_hi(lo.x) + bf_hi(hi.x);
                ei[4 * q + 0] = bf_lo(lo.x) + bf_lo(hi.x);
                er[4 * q + 1] = bf_hi(lo.y) + bf_hi(hi.y);
                ei[4 * q + 1] = bf_lo(lo.y) + bf_lo(hi.y);
                er[4 * q + 2] = bf_hi(lo.z) + bf_hi(hi.z);
                ei[4 * q + 2] = bf_lo(lo.z) + bf_lo(hi.z);
                er[4 * q + 3] = bf_hi(lo.w) + bf_hi(hi.w);
                ei[4 * q + 3] = bf_lo(lo.w) + bf_lo(hi.w);
            }
            fft16(er, ei);
            if (slot == 0) {
#pragma unroll
                for (int k2 = 0; k2 <= 8; ++k2) {
                    const int kr = 2 * k2;
                    const int b = (k2 == 0) ? 0 : 16 - k2;
                    const float g0r = 0.5f * (er[k2] + er[b]);
                    const float g0i = 0.5f * (ei[k2] - ei[b]);
                    const float g1r = 0.5f * (ei[k2] + ei[b]);
                    const float g1i = 0.5f * (er[b] - er[k2]);
                    const float w0c = (kr >= 7 ? 1.0f : 0.0f) + ((kr >= 8 && kr <= 15) ? 1.0f : 0.0f);
                    const float w16c = 1.0f + ((kr >= 1 && kr <= 15) ? 1.0f : 0.0f);
                    if (w0c > 0.0f)
                        s0 = fmaf(w0c, __logf(g0r * g0r + g0i * g0i + 1.0f), s0);
                    s1 = fmaf(w16c, __logf(g1r * g1r + g1i * g1i + 1.0f), s1);
                }
            } else {
#pragma unroll
                for (int k2 = 0; k2 < 16; ++k2) {
                    const int kr = 2 * k2;
                    const float lp = __logf(er[k2] * er[k2] + ei[k2] * ei[k2] + 1.0f);
                    const float wgt = (kr >= 8 && kr <= 24) ? 2.0f : (b1f + m1f);
                    if (k2 & 1) s1 = fmaf(wgt, lp, s1);
                    else        s0 = fmaf(wgt, lp, s0);
                }
            }
        }

        // ---- pass 2: odd kr (re-read LDS, premix with twiddle) ----
        {
            float orr[16], oi[16];
#pragma unroll
            for (int q = 0; q < 4; ++q) {
                const uint4 lo = p4[q];
                const uint4 hi = p4[q + 4];
#pragma unroll
                for (int j = 0; j < 4; ++j) {
                    const unsigned ul = (&lo.x)[j];
                    const unsigned uh = (&hi.x)[j];
                    const int i = 4 * q + j;
                    const float dre = bf_hi(ul) - bf_hi(uh);
                    const float dim = bf_lo(ul) - bf_lo(uh);
                    orr[i] = dre * C32[i] + dim * S32[i];
                    oi[i]  = dim * C32[i] - dre * S32[i];
                }
            }
            fft16(orr, oi);
            if (slot == 0) {
#pragma unroll
                for (int k2 = 0; k2 <= 7; ++k2) {
                    const int kr = 2 * k2 + 1;
                    const int b = 15 - k2;
                    const float g0r = 0.5f * (orr[k2] + orr[b]);
                    const float g0i = 0.5f * (oi[k2] - oi[b]);
                    const float g1r = 0.5f * (oi[k2] + oi[b]);
                    const float g1i = 0.5f * (orr[b] - orr[k2]);
                    const float w0c = (kr >= 7 ? 1.0f : 0.0f) + ((kr >= 8 && kr <= 15) ? 1.0f : 0.0f);
                    const float w16c = 2.0f;   // kr in [1,15]
                    if (w0c > 0.0f)
                        s0 = fmaf(w0c, __logf(g0r * g0r + g0i * g0i + 1.0f), s0);
                    s1 = fmaf(w16c, __logf(g1r * g1r + g1i * g1i + 1.0f), s1);
                }
            } else {
#pragma unroll
                for (int k2 = 0; k2 < 16; ++k2) {
                    const int kr = 2 * k2 + 1;
                    const float lp = __logf(orr[k2] * orr[k2] + oi[k2] * oi[k2] + 1.0f);
                    float wgt;
                    if (kr == 7)                   wgt = 1.0f + m1f;
                    else if (kr == 25)             wgt = b1f + 1.0f;
                    else if (kr >= 9 && kr <= 23)  wgt = 2.0f;
                    else                           wgt = b1f + m1f;
                    if (k2 & 1) s1 = fmaf(wgt, lp, s1);
                    else        s0 = fmaf(wgt, lp, s0);
                }
            }
        }

        float s = s0 + s1;
#pragma unroll
        for (int off = 8; off >= 1; off >>= 1) s += __shfl_xor(s, off, 16);
        if (slot == 0) {
            out[(blockIdx.y * 8 + ph) * mat_w + blockIdx.x * 2 + strip] = s;
            red[pl] = s;
        }
    }

    __syncthreads();

    if (tid == 0) {
        float m = red[0];
#pragma unroll
        for (int i = 1; i < 16; ++i) m = fmaxf(m, red[i]);
        partial[blockIdx.y * gridDim.x + blockIdx.x] = m;
    }
}

// ===================== FALLBACK (R10, proven) =====================
__global__ __launch_bounds__(256) void gray_kernel(
        const float* __restrict__ x, const float* __restrict__ w,
        float* __restrict__ g, int n4, long long HW) {
    const int i = blockIdx.x * 256 + threadIdx.x;
    if (i >= n4) return;
    const float w0 = w[0], w1 = w[1], w2 = w[2];
    const float4 a = reinterpret_cast<const float4*>(x)[i];
    const float4 b = reinterpret_cast<const float4*>(x + HW)[i];
    const float4 c = reinterpret_cast<const float4*>(x + 2 * HW)[i];
    float4 o;
    o.x = w0 * a.x + w1 * b.x + w2 * c.x;
    o.y = w0 * a.y + w1 * b.y + w2 * c.y;
    o.z = w0 * a.z + w1 * b.z + w2 * c.z;
    o.w = w0 * a.w + w1 * b.w + w2 * c.w;
    reinterpret_cast<float4*>(g)[i] = o;
}

template <bool GRAY_PRE>
__global__ __launch_bounds__(128) void hfdft_patch_kernel(
        const float* __restrict__ x, const float* __restrict__ w,
        float* __restrict__ out, int H, int W, int mat_h, int mat_w) {
    __shared__ unsigned cb[4 * 528];
    __shared__ float red[8];

    const int tid = threadIdx.x;
    const int h = tid >> 6;
    const int lane = tid & 63;
    const int total = mat_h * mat_w;
    const long long HW = (long long)H * W;
    const int Pbase = blockIdx.x * 4;

    {
        const int g = lane >> 5, r = lane & 31;
        int pA = Pbase + 2 * g;
        if (pA > total - 1) pA = total - 1;
        int pB = pA + 1; if (pB > total - 1) pB = total - 1;
        const int phA = pA / mat_w, pwA = pA % mat_w;
        const int phB = pB / mat_w, pwB = pB % mat_w;
        const bool adj = (phA == phB) && (pwB == pwA + 1);
        const int baseA = (phA * SCALE + r) * W + pwA * SCALE;
        const int baseB = (phB * SCALE + r) * W + pwB * SCALE;

        float ar[32], br[32];
        if (GRAY_PRE && adj) {
            float win2[40];
            const float4* g4 = reinterpret_cast<const float4*>(x + baseA);
#pragma unroll
            for (int q = 0; q < 10; ++q) {
                const float4 v = g4[q];
                win2[4 * q + 0] = v.x; win2[4 * q + 1] = v.y;
                win2[4 * q + 2] = v.z; win2[4 * q + 3] = v.w;
            }
#pragma unroll
            for (int i = 0; i < 32; ++i) { ar[i] = win2[i]; br[i] = win2[i + 8]; }
        } else if (GRAY_PRE) {
#pragma unroll
            for (int i = 0; i < 32; ++i) { ar[i] = x[baseA + i]; br[i] = x[baseB + i]; }
        } else {
            const float w0 = w[0], w1 = w[1], w2 = w[2];
#pragma unroll
            for (int i = 0; i < 32; ++i) {
                ar[i] = w0 * x[baseA + i] + w1 * x[HW + baseA + i] + w2 * x[2 * HW + baseA + i];
                br[i] = w0 * x[baseB + i] + w1 * x[HW + baseB + i] + w2 * x[2 * HW + baseB + i];
            }
        }

        float fr[16], fi[16];
        if (h == 0) {
#pragma unroll
            for (int i = 0; i < 16; ++i) {
                fr[i] = ar[i] + ar[i + 16];
                fi[i] = br[i] + br[i + 16];
            }
        } else {
#pragma unroll
            for (int i = 0; i < 16; ++i) {
                const float dre = ar[i] - ar[i + 16];
                const float dim = br[i] - br[i + 16];
                fr[i] = dre * C32[i] + dim * S32[i];
                fi[i] = dim * C32[i] - dre * S32[i];
            }
        }

        fft16(fr, fi);

        unsigned* cbA = cb + (2 * g) * 528;
        unsigned* cbB = cbA + 528;
        if (h == 0) {
            cbA[r] = pack_bf2(fr[0], fr[8]);
            cbB[r] = pack_bf2(fi[0], fi[8]);
#pragma unroll
            for (int k2 = 1; k2 <= 7; ++k2) {
                const int e2 = 16 - k2;
                const float far_ = 0.5f * (fr[k2] + fr[e2]);
                const float fai_ = 0.5f * (fi[k2] - fi[e2]);
                const float fbr_ = 0.5f * (fi[k2] + fi[e2]);
                const float fbi_ = 0.5f * (fr[e2] - fr[k2]);
                cbA[(2 * k2) * 33 + r] = pack_bf2(far_, fai_);
                cbB[(2 * k2) * 33 + r] = pack_bf2(fbr_, fbi_);
            }
        } else {
#pragma unroll
            for (int k2 = 0; k2 <= 7; ++k2) {
                const int o2 = 15 - k2;
                const float far_ = 0.5f * (fr[k2] + fr[o2]);
                const float fai_ = 0.5f * (fi[k2] - fi[o2]);
                const float fbr_ = 0.5f * (fi[k2] + fi[o2]);
                const float fbi_ = 0.5f * (fr[o2] - fr[k2]);
                cbA[(2 * k2 + 1) * 33 + r] = pack_bf2(far_, fai_);
                cbB[(2 * k2 + 1) * 33 + r] = pack_bf2(fbr_, fbi_);
            }
        }
    }

    __syncthreads();

    {
        const int pl = lane >> 4, slot = lane & 15;
        int p = Pbase + pl;
        if (p > total - 1) p = total - 1;
        const unsigned* cbp = cb + pl * 528 + slot * 33;

        float fr[16], fi[16];
        if (h == 0) {
#pragma unroll
            for (int i = 0; i < 16; ++i) {
                const unsigned u0 = cbp[i], u1 = cbp[i + 16];
                fr[i] = bf_hi(u0) + bf_hi(u1);
                fi[i] = bf_lo(u0) + bf_lo(u1);
            }
        } else {
#pragma unroll
            for (int i = 0; i < 16; ++i) {
                const unsigned u0 = cbp[i], u1 = cbp[i + 16];
                const float dre = bf_hi(u0) - bf_hi(u1);
                const float dim = bf_lo(u0) - bf_lo(u1);
                fr[i] = dre * C32[i] + dim * S32[i];
                fi[i] = dim * C32[i] - dre * S32[i];
            }
        }

        fft16(fr, fi);

        float s0 = 0.0f, s1 = 0.0f;
        if (slot == 0) {
            if (h == 0) {
#pragma unroll
                for (int k2 = 0; k2 <= 8; ++k2) {
                    const int kr = 2 * k2;
                    const int b = (k2 == 0) ? 0 : 16 - k2;
                    const float g0r = 0.5f * (fr[k2] + fr[b]);
                    const float g0i = 0.5f * (fi[k2] - fi[b]);
                    const float g1r = 0.5f * (fi[k2] + fi[b]);
                    const float g1i = 0.5f * (fr[b] - fr[k2]);
                    const float w0c = (kr >= 7 ? 1.0f : 0.0f) + ((kr >= 8 && kr <= 15) ? 1.0f : 0.0f);
                    const float w16c = 1.0f + ((kr >= 1 && kr <= 15) ? 1.0f : 0.0f);
                    if (w0c > 0.0f)
                        s0 = fmaf(w0c, __logf(g0r * g0r + g0i * g0i + 1.0f), s0);
                    s1 = fmaf(w16c, __logf(g1r * g1r + g1i * g1i + 1.0f), s1);
                }
            } else {
#pragma unroll
                for (int k2 = 0; k2 <= 7; ++k2) {
                    const int kr = 2 * k2 + 1;
                    const int b = 15 - k2;
                    const float g0r = 0.5f * (fr[k2] + fr[b]);
                    const float g0i = 0.5f * (fi[k2] - fi[b]);
                    const float g1r = 0.5f * (fi[k2] + fi[b]);
                    const float g1i = 0.5f * (fr[b] - fr[k2]);
                    const float w0c = (kr >= 7 ? 1.0f : 0.0f) + ((kr >= 8 && kr <= 15) ? 1.0f : 0.0f);
                    const float w16c = 2.0f;
                    if (w0c > 0.0f)
                        s0 = fmaf(w0c, __logf(g0r * g0r + g0i * g0i + 1.0f), s0);
                    s1 = fmaf(w16c, __logf(g1r * g1r + g1i * g1i + 1.0f), s1);
                }
            }
        } else {
            const float b1f = (slot >= 7) ? 1.0f : 0.0f;
            const float m1f = (slot >= 8) ? 1.0f : 0.0f;
            if (h == 0) {
#pragma unroll
                for (int k2 = 0; k2 < 16; ++k2) {
                    const int kr = 2 * k2;
                    const float lp = __logf(fr[k2] * fr[k2] + fi[k2] * fi[k2] + 1.0f);
                    const float wgt = (kr >= 8 && kr <= 24) ? 2.0f : (b1f + m1f);
                    if (k2 & 1) s1 = fmaf(wgt, lp, s1);
                    else        s0 = fmaf(wgt, lp, s0);
                }
            } else {
#pragma unroll
                for (int k2 = 0; k2 < 16; ++k2) {
                    const int kr = 2 * k2 + 1;
                    const float lp = __logf(fr[k2] * fr[k2] + fi[k2] * fi[k2] + 1.0f);
                    float wgt;
                    if (kr == 7)                   wgt = 1.0f + m1f;
                    else if (kr == 25)             wgt = b1f + 1.0f;
                    else if (kr >= 9 && kr <= 23)  wgt = 2.0f;
                    else                           wgt = b1f + m1f;
                    if (k2 & 1) s1 = fmaf(wgt, lp, s1);
                    else        s0 = fmaf(wgt, lp, s0);
                }
            }
        }

        float s = s0 + s1;
#pragma unroll
        for (int off = 8; off >= 1; off >>= 1) s += __shfl_xor(s, off, 16);
        if (slot == 0) red[pl * 2 + h] = s;
    }

    __syncthreads();

    if (tid < 4) {
        const int p = Pbase + tid;
        if (p < total) out[p] = red[tid * 2] + red[tid * 2 + 1];
    }
}

__global__ __launch_bounds__(1024) void max_kernel(
        const float* __restrict__ sums, int n, float* __restrict__ partial) {
    __shared__ float sm[16];
    float m = 0.0f;  // sums are >= 0
    for (int i = blockIdx.x * 1024 + threadIdx.x; i < n; i += gridDim.x * 1024)
        m = fmaxf(m, sums[i]);
#pragma unroll
    for (int off = 32; off >= 1; off >>= 1) m = fmaxf(m, __shfl_xor(m, off, 64));
    if ((threadIdx.x & 63) == 0) sm[threadIdx.x >> 6] = m;
    __syncthreads();
    if (threadIdx.x == 0) {
#pragma unroll
        for (int i = 1; i < 16; ++i) m = fmaxf(m, sm[i]);
        partial[blockIdx.x] = m;
    }
}

// norm: inline max-reduce over np partials, then divide
__global__ __launch_bounds__(256) void norm_kernel(
        float* __restrict__ out, int n,
        const float* __restrict__ partial, int np) {
    __shared__ float sm[4];
    float m = 0.0f;  // partials are >= 0
    for (int i = threadIdx.x; i < np; i += 256) m = fmaxf(m, partial[i]);
#pragma unroll
    for (int off = 32; off >= 1; off >>= 1) m = fmaxf(m, __shfl_xor(m, off, 64));
    if ((threadIdx.x & 63) == 0) sm[threadIdx.x >> 6] = m;
    __syncthreads();
    m = fmaxf(fmaxf(sm[0], sm[1]), fmaxf(sm[2], sm[3]));
    const int i = blockIdx.x * 256 + threadIdx.x;
    if (i < n) out[i] = out[i] / m;
}

extern "C" void kernel_launch(void* const* d_in, const int* in_sizes, int n_in,
                              void* d_out, int out_size, void* d_ws, size_t ws_size,
                              hipStream_t stream) {
    const float* x = (const float*)d_in[0];
    const float* w = (const float*)d_in[1];
    float* out = (float*)d_out;

    const int HWi = in_sizes[0] / 3;
    const int H = (int)(sqrt((double)HWi) + 0.5);
    const int W = H;
    const long long HW = (long long)H * W;
    const int mat = (int)(sqrt((double)out_size) + 0.5);
    const int total = mat * mat;

    float* partial = (float*)d_ws;
    float* gray = (float*)((char*)d_ws + 8192);
    const int nparts = (mat / 2) * (mat / 8);
    const size_t need_fb = 8192 + (size_t)HW * 4;

    const bool shape_ok = ((mat & 7) == 0) && (W == (mat - 1) * SCALE + PSZ)
                          && (H == W) && ((W & 3) == 0)
                          && ws_size >= (size_t)nparts * 4;

    if (shape_ok) {
        dim3 gridT(mat / 2, mat / 8);
        hipLaunchKernelGGL(hfdft_tile_kernel, gridT, dim3(256), 0, stream,
                           x, w, out, partial, W, mat, HW);
        hipLaunchKernelGGL(norm_kernel, dim3((total + 255) / 256), dim3(256), 0, stream,
                           out, total, partial, nparts);
    } else if (ws_size >= need_fb && (W & 3) == 0) {
        const int n4 = (int)(HW / 4);
        hipLaunchKernelGGL(gray_kernel, dim3((n4 + 255) / 256), dim3(256), 0, stream,
                           x, w, gray, n4, HW);
        hipLaunchKernelGGL((hfdft_patch_kernel<true>), dim3((total + 3) / 4), dim3(128), 0, stream,
                           gray, w, out, H, W, mat, mat);
        hipLaunchKernelGGL(max_kernel, dim3(8), dim3(1024), 0, stream, out, total, partial);
        hipLaunchKernelGGL(norm_kernel, dim3((total + 255) / 256), dim3(256), 0, stream,
                           out, total, partial, 8);
    } else {
        hipLaunchKernelGGL((hfdft_patch_kernel<false>), dim3((total + 3) / 4), dim3(128), 0, stream,
                           x, w, out, H, W, mat, mat);
        hipLaunchKernelGGL(max_kernel, dim3(8), dim3(1024), 0, stream, out, total, partial);
        hipLaunchKernelGGL(norm_kernel, dim3((total + 255) / 256), dim3(256), 0, stream,
                           out, total, partial, 8);
    }
}

// Round 15
// 41.998 us; speedup vs baseline: 1.0785x; 1.0785x over previous
//
#include <hip/hip_runtime.h>
#include <math.h>

#define SCALE 8
#define PSZ 32

// ---- constant twiddles: W_32^k = cos(2pi k/32) - i sin(2pi k/32), k=0..15 ----
__device__ constexpr float C32[16] = {
     1.000000000000000f,  0.980785280403230f,  0.923879532511287f,  0.831469612302545f,
     0.707106781186548f,  0.555570233019602f,  0.382683432365090f,  0.195090322016128f,
     0.000000000000000f, -0.195090322016128f, -0.382683432365090f, -0.555570233019602f,
    -0.707106781186548f, -0.831469612302545f, -0.923879532511287f, -0.980785280403230f };
__device__ constexpr float S32[16] = {
     0.000000000000000f,  0.195090322016128f,  0.382683432365090f,  0.555570233019602f,
     0.707106781186548f,  0.831469612302545f,  0.923879532511287f,  0.980785280403230f,
     1.000000000000000f,  0.980785280403230f,  0.923879532511287f,  0.831469612302545f,
     0.707106781186548f,  0.555570233019602f,  0.382683432365090f,  0.195090322016128f };

__device__ __forceinline__ constexpr int brev5(int i) {
    return ((i & 1) << 4) | ((i & 2) << 2) | (i & 4) | ((i & 8) >> 2) | ((i & 16) >> 4);
}

// in-place 32-point radix-2 DIT FFT, fully unrolled (R1-verified; best-bench R8 used this)
__device__ __forceinline__ void fft32(float re[PSZ], float im[PSZ]) {
#pragma unroll
    for (int i = 0; i < 32; ++i) {
        const int j = brev5(i);
        if (j > i) {
            float t = re[i]; re[i] = re[j]; re[j] = t;
            t = im[i]; im[i] = im[j]; im[j] = t;
        }
    }
#pragma unroll
    for (int s = 1; s <= 5; ++s) {
        const int m = 1 << s;
        const int h = m >> 1;
        const int tstep = 32 >> s;
#pragma unroll
        for (int k = 0; k < 32; k += m) {
#pragma unroll
            for (int j = 0; j < h; ++j) {
                const float wr = C32[j * tstep];
                const float wi = -S32[j * tstep];
                const int a = k + j;
                const int b = k + j + h;
                const float tr = wr * re[b] - wi * im[b];
                const float ti = wr * im[b] + wi * re[b];
                re[b] = re[a] - tr; im[b] = im[a] - ti;
                re[a] = re[a] + tr; im[a] = im[a] + ti;
            }
        }
    }
}

// bf16x2 pack/unpack (round-half-up via +0x8000)
__device__ __forceinline__ unsigned pack_bf2(float hi, float lo) {
    const unsigned uh = __float_as_uint(hi) + 0x8000u;
    const unsigned ul = __float_as_uint(lo) + 0x8000u;
    return (uh & 0xFFFF0000u) | (ul >> 16);
}
__device__ __forceinline__ float bf_hi(unsigned u) { return __uint_as_float(u & 0xFFFF0000u); }
__device__ __forceinline__ float bf_lo(unsigned u) { return __uint_as_float(u << 16); }

// ---- gray precompute: g = w0*R + w1*G + w2*B, vectorized float4 (R4-proven) ----
__global__ __launch_bounds__(256) void gray_kernel(
        const float* __restrict__ x, const float* __restrict__ w,
        float* __restrict__ g, int n4, long long HW) {
    const int i = blockIdx.x * 256 + threadIdx.x;
    if (i >= n4) return;
    const float w0 = w[0], w1 = w[1], w2 = w[2];
    const float4 a = reinterpret_cast<const float4*>(x)[i];
    const float4 b = reinterpret_cast<const float4*>(x + HW)[i];
    const float4 c = reinterpret_cast<const float4*>(x + 2 * HW)[i];
    float4 o;
    o.x = w0 * a.x + w1 * b.x + w2 * c.x;
    o.y = w0 * a.y + w1 * b.y + w2 * c.y;
    o.z = w0 * a.z + w1 * b.z + w2 * c.z;
    o.w = w0 * a.w + w1 * b.w + w2 * c.w;
    reinterpret_cast<float4*>(g)[i] = o;
}

// ===================== PATCH KERNEL (R8 best-bench config + fused block max) =====================
// 128-thread block = 2 independent waves; each wave handles 4 patches in its
// own private LDS slab (wave-local lgkmcnt fence instead of s_barrier).
// Row stage: lane (g=lane>>5, r=lane&31) packs row r of patches (2g, 2g+1) as
// a + i*b -> ONE complex FFT32 -> unpack the two real-row spectra (Hermitian:
// k=0..16; k=0 & 16 real, packed into slot 0). LDS bf16x2, stride 33
// (2-way bank aliasing only = free; SQ_LDS_BANK_CONFLICT == 0 measured).
// Col stage: lane (pl=lane>>4, slot=lane&15): 15 complex column FFTs + 1
// packed real-pair FFT per patch; masked log-power with Hermitian mirror
// weights {0,1,2}; 16-lane shuffle reduce.
// NEW vs R8: block writes ONE partial max (plain store) -> max_kernel dropped.
template <bool GRAY_PRE>
__global__ __launch_bounds__(128)
__attribute__((amdgpu_waves_per_eu(2, 4)))
void hfdft_patch_kernel(
        const float* __restrict__ x, const float* __restrict__ w,
        float* __restrict__ out, float* __restrict__ partial,
        int H, int W, int mat_h, int mat_w) {
    __shared__ unsigned cb[8 * 528];   // 2 waves * 4 patches * 528 u32
    __shared__ float red[8];

    const int tid = threadIdx.x;
    const int wid = tid >> 6;
    const int lane = tid & 63;
    const int P0 = blockIdx.x * 8 + wid * 4;
    const int total = mat_h * mat_w;
    const long long HW = (long long)H * W;
    unsigned* cbw = cb + wid * 4 * 528;   // this wave's private slab

    // ================= row stage =================
    {
        const int g = lane >> 5, r = lane & 31;
        int pA = P0 + 2 * g;
        if (pA > total - 1) pA = total - 1;
        int pB = pA + 1; if (pB > total - 1) pB = total - 1;
        const int phA = pA / mat_w, pwA = pA % mat_w;
        const int phB = pB / mat_w, pwB = pB % mat_w;
        const bool adj = (phA == phB) && (pwB == pwA + 1);

        float re[PSZ], im[PSZ];
        if (GRAY_PRE) {
            if (adj) {
                const int base = (phA * SCALE + r) * W + pwA * SCALE;
                const float4* g4 = reinterpret_cast<const float4*>(x + base);
                float win[40];
#pragma unroll
                for (int q = 0; q < 10; ++q) {
                    const float4 v = g4[q];
                    win[4 * q + 0] = v.x; win[4 * q + 1] = v.y;
                    win[4 * q + 2] = v.z; win[4 * q + 3] = v.w;
                }
#pragma unroll
                for (int i = 0; i < PSZ; ++i) { re[i] = win[i]; im[i] = win[i + 8]; }
            } else {
                const int baseA = (phA * SCALE + r) * W + pwA * SCALE;
                const int baseB = (phB * SCALE + r) * W + pwB * SCALE;
#pragma unroll
                for (int i = 0; i < PSZ; ++i) { re[i] = x[baseA + i]; im[i] = x[baseB + i]; }
            }
        } else {
            const float w0 = w[0], w1 = w[1], w2 = w[2];
            if (adj && ((W & 3) == 0)) {
                const int base = (phA * SCALE + r) * W + pwA * SCALE;
                const float4* a4 = reinterpret_cast<const float4*>(x + base);
                const float4* b4 = reinterpret_cast<const float4*>(x + HW + base);
                const float4* c4 = reinterpret_cast<const float4*>(x + 2 * HW + base);
                float win[40];
#pragma unroll
                for (int q = 0; q < 10; ++q) {
                    const float4 a = a4[q], b = b4[q], c = c4[q];
                    win[4 * q + 0] = w0 * a.x + w1 * b.x + w2 * c.x;
                    win[4 * q + 1] = w0 * a.y + w1 * b.y + w2 * c.y;
                    win[4 * q + 2] = w0 * a.z + w1 * b.z + w2 * c.z;
                    win[4 * q + 3] = w0 * a.w + w1 * b.w + w2 * c.w;
                }
#pragma unroll
                for (int i = 0; i < PSZ; ++i) { re[i] = win[i]; im[i] = win[i + 8]; }
            } else {
                const int baseA = (phA * SCALE + r) * W + pwA * SCALE;
                const int baseB = (phB * SCALE + r) * W + pwB * SCALE;
#pragma unroll
                for (int i = 0; i < PSZ; ++i) {
                    re[i] = w0 * x[baseA + i] + w1 * x[HW + baseA + i] + w2 * x[2 * HW + baseA + i];
                    im[i] = w0 * x[baseB + i] + w1 * x[HW + baseB + i] + w2 * x[2 * HW + baseB + i];
                }
            }
        }

        fft32(re, im);   // FFT of rowA + i*rowB

        unsigned* cbA = cbw + (2 * g) * 528;
        unsigned* cbB = cbA + 528;
        cbA[r] = pack_bf2(re[0], re[16]);
        cbB[r] = pack_bf2(im[0], im[16]);
#pragma unroll
        for (int k = 1; k <= 15; ++k) {
            const int m = 32 - k;
            const float far_ = 0.5f * (re[k] + re[m]);
            const float fai_ = 0.5f * (im[k] - im[m]);
            const float fbr_ = 0.5f * (im[k] + im[m]);
            const float fbi_ = 0.5f * (re[m] - re[k]);
            cbA[k * 33 + r] = pack_bf2(far_, fai_);
            cbB[k * 33 + r] = pack_bf2(fbr_, fbi_);
        }
    }

    // waves don't share LDS slabs: wave-local fence (no s_barrier here)
    asm volatile("s_waitcnt lgkmcnt(0)" ::: "memory");

    // ================= column stage =================
    {
        const int pl = lane >> 4, slot = lane & 15;
        const int p = P0 + pl;
        const unsigned* cbp = cbw + pl * 528 + slot * 33;

        float cre[PSZ], cim[PSZ];
#pragma unroll
        for (int r2 = 0; r2 < PSZ; ++r2) {
            const unsigned u = cbp[r2];
            cre[r2] = bf_hi(u);
            cim[r2] = bf_lo(u);
        }

        fft32(cre, cim);

        float s0 = 0.0f, s1 = 0.0f;
        if (slot == 0) {
            // packed pair (col 0, col 16): unpack kr=0..16, Hermitian-in-kr weights
#pragma unroll
            for (int kr = 0; kr <= 16; ++kr) {
                const int m = (32 - kr) & 31;
                const float g0r = 0.5f * (cre[kr] + cre[m]);
                const float g0i = 0.5f * (cim[kr] - cim[m]);
                const float g1r = 0.5f * (cim[kr] + cim[m]);
                const float g1i = 0.5f * (cre[m] - cre[kr]);
                const float w0c = (kr >= 7 ? 1.0f : 0.0f) + ((kr >= 8 && kr <= 15) ? 1.0f : 0.0f);
                const float w16c = 1.0f + ((kr >= 1 && kr <= 15) ? 1.0f : 0.0f);
                if (w0c > 0.0f)
                    s0 = fmaf(w0c, __logf(g0r * g0r + g0i * g0i + 1.0f), s0);
                s1 = fmaf(w16c, __logf(g1r * g1r + g1i * g1i + 1.0f), s1);
            }
        } else {
            const float b1f = (slot >= 7) ? 1.0f : 0.0f;
            const float m1f = (slot >= 8) ? 1.0f : 0.0f;
#pragma unroll
            for (int kr = 0; kr < 32; ++kr) {
                const float lp = __logf(cre[kr] * cre[kr] + cim[kr] * cim[kr] + 1.0f);
                float wgt;
                if (kr >= 8 && kr <= 24)      wgt = 2.0f;
                else if (kr == 7)             wgt = 1.0f + m1f;
                else if (kr == 25)            wgt = b1f + 1.0f;
                else                          wgt = b1f + m1f;
                if (kr & 1) s1 = fmaf(wgt, lp, s1);
                else        s0 = fmaf(wgt, lp, s0);
            }
        }
        float s = s0 + s1;

#pragma unroll
        for (int off = 8; off >= 1; off >>= 1) s += __shfl_xor(s, off, 16);
        if (slot == 0) {
            if (p < total) out[p] = s;
            red[wid * 4 + pl] = s;   // duplicates (clamped p) repeat real values: max unaffected
        }
    }

    __syncthreads();

    if (tid == 0) {
        float m = red[0];
#pragma unroll
        for (int i = 1; i < 8; ++i) m = fmaxf(m, red[i]);
        partial[blockIdx.x] = m;
    }
}

// norm: inline max-reduce over np partials (np = #blocks of patch kernel), then divide
__global__ __launch_bounds__(256) void norm_kernel(
        float* __restrict__ out, int n,
        const float* __restrict__ partial, int np) {
    __shared__ float sm[4];
    float m = 0.0f;  // partials are >= 0
    for (int i = threadIdx.x; i < np; i += 256) m = fmaxf(m, partial[i]);
#pragma unroll
    for (int off = 32; off >= 1; off >>= 1) m = fmaxf(m, __shfl_xor(m, off, 64));
    if ((threadIdx.x & 63) == 0) sm[threadIdx.x >> 6] = m;
    __syncthreads();
    m = fmaxf(fmaxf(sm[0], sm[1]), fmaxf(sm[2], sm[3]));
    const int i = blockIdx.x * 256 + threadIdx.x;
    if (i < n) out[i] = out[i] / m;
}

extern "C" void kernel_launch(void* const* d_in, const int* in_sizes, int n_in,
                              void* d_out, int out_size, void* d_ws, size_t ws_size,
                              hipStream_t stream) {
    const float* x = (const float*)d_in[0];
    const float* w = (const float*)d_in[1];
    float* out = (float*)d_out;

    const int HWi = in_sizes[0] / 3;
    const int H = (int)(sqrt((double)HWi) + 0.5);
    const int W = H;
    const long long HW = (long long)H * W;
    const int mat = (int)(sqrt((double)out_size) + 0.5);
    const int total = mat * mat;
    const int blocksA = (total + 7) / 8;

    float* partial = (float*)d_ws;                        // blocksA floats
    const size_t part_bytes = ((size_t)blocksA * 4 + 255) & ~(size_t)255;
    float* gray = (float*)((char*)d_ws + part_bytes);
    const size_t need = part_bytes + (size_t)HW * 4;

    if (ws_size >= need && (W & 3) == 0) {
        const int n4 = (int)(HW / 4);
        hipLaunchKernelGGL(gray_kernel, dim3((n4 + 255) / 256), dim3(256), 0, stream,
                           x, w, gray, n4, HW);
        hipLaunchKernelGGL((hfdft_patch_kernel<true>), dim3(blocksA), dim3(128), 0, stream,
                           gray, w, out, partial, H, W, mat, mat);
    } else {
        hipLaunchKernelGGL((hfdft_patch_kernel<false>), dim3(blocksA), dim3(128), 0, stream,
                           x, w, out, partial, H, W, mat, mat);
    }
    hipLaunchKernelGGL(norm_kernel, dim3((total + 255) / 256), dim3(256), 0, stream,
                       out, total, partial, blocksA);
}